// Round 3
// baseline (2666.870 us; speedup 1.0000x reference)
//
#include <hip/hip_runtime.h>
#include <hip/hip_fp16.h>

typedef _Float16 half8 __attribute__((ext_vector_type(8)));
typedef _Float16 half2v __attribute__((ext_vector_type(2)));
typedef float f32x4 __attribute__((ext_vector_type(4)));

#define T_STEPS 1024
#define INC 128
#define HIDC 256
#define G3 768
#define NN 100000
#define KSPLIT 32
#define NCHUNK 3125   // NN / KSPLIT
#define XS_STRIDE 144 // 16 c-groups * 8 + skew(12) + hf(4): max offset 139 -> stride 144

// quad_perm [1,0,3,2] : xor-1 within each quad, pure-VALU lane exchange
__device__ __forceinline__ float dpp_xor1(float v){
  int t = __builtin_amdgcn_update_dpp(0, __float_as_int(v), 0xB1, 0xF, 0xF, true);
  return __int_as_float(t);
}
// quad_perm [2,3,0,1] : xor-2 within each quad
__device__ __forceinline__ float dpp_xor2(float v){
  int t = __builtin_amdgcn_update_dpp(0, __float_as_int(v), 0x4E, 0xF, 0xF, true);
  return __int_as_float(t);
}

// ---------------- Phase 1: partials[ks][t][c] = sum over n-chunk of H[n,t]*X[n,c]
// 256 blocks (1D, XCD-swizzled), 512 threads, tile 128t x 128c, thread-tile 4x8.
__global__ __launch_bounds__(512) void k_phase1(const float* __restrict__ X,
                                                const float* __restrict__ Hm,
                                                float* __restrict__ part){
  const int bid = blockIdx.x;         // 0..255
  const int xcd = bid & 7;
  const int idx = bid >> 3;           // 0..31
  const int ks  = xcd * 4 + (idx & 3);
  const int tt  = idx >> 2;           // 0..7
  const int t0 = tt * 128;
  const int nbeg = ks * NCHUNK;
  const int nend = nbeg + NCHUNK;
  __shared__ float Hs[16][128];
  __shared__ float Xs[16 * XS_STRIDE];   // bank-skewed, stride 144
  const int tid = threadIdx.x;
  const int tx = tid & 15;            // c-group: c0 = tx*8
  const int ty = tid >> 4;            // 0..31 : t rows ty*4..+3
  const int sr = tid >> 5;            // staging row 0..15
  const int sc = tid & 31;            // staging float4 col
  const int xskew = tx * 8 + (tx >> 2) * 4;   // 2-way max bank aliasing

  float acc[4][8];
  #pragma unroll
  for (int r = 0; r < 4; r++)
    #pragma unroll
    for (int q = 0; q < 8; q++) acc[r][q] = 0.f;

  // prologue prefetch (iter 0)
  float4 hv = make_float4(0.f,0.f,0.f,0.f), xv = make_float4(0.f,0.f,0.f,0.f);
  {
    int n = nbeg + sr;
    if (n < nend){
      hv = *(const float4*)(Hm + (size_t)n * T_STEPS + t0 + sc * 4);
      xv = *(const float4*)(X  + (size_t)n * INC + sc * 4);
    }
  }

  for (int n0 = nbeg; n0 < nend; n0 += 16){
    __builtin_amdgcn_s_barrier();     // prev tile's readers done (their own lgkm drained)
    asm volatile("" ::: "memory");
    *(float4*)&Hs[sr][sc * 4] = hv;
    {
      int g = sc >> 1, hf = sc & 1;   // c-group, half
      *(float4*)&Xs[sr * XS_STRIDE + g * 8 + (g >> 2) * 4 + hf * 4] = xv;
    }
    asm volatile("s_waitcnt lgkmcnt(0)" ::: "memory");
    __builtin_amdgcn_s_barrier();     // tile visible to all waves
    asm volatile("" ::: "memory");

    // issue next tile's loads NOW; FMA phase below hides HBM latency
    {
      int nn = n0 + 16 + sr;
      hv = make_float4(0.f,0.f,0.f,0.f);
      xv = make_float4(0.f,0.f,0.f,0.f);
      if (nn < nend){
        hv = *(const float4*)(Hm + (size_t)nn * T_STEPS + t0 + sc * 4);
        xv = *(const float4*)(X  + (size_t)nn * INC + sc * 4);
      }
    }

    #pragma unroll
    for (int i = 0; i < 16; i++){
      float4 h4 = *(const float4*)&Hs[i][ty * 4];
      float4 x0 = *(const float4*)&Xs[i * XS_STRIDE + xskew];
      float4 x1 = *(const float4*)&Xs[i * XS_STRIDE + xskew + 4];
      float xr[8] = {x0.x,x0.y,x0.z,x0.w,x1.x,x1.y,x1.z,x1.w};
      float hr[4] = {h4.x,h4.y,h4.z,h4.w};
      #pragma unroll
      for (int r = 0; r < 4; r++)
        #pragma unroll
        for (int q = 0; q < 8; q++)
          acc[r][q] += hr[r] * xr[q];
    }
  }
  #pragma unroll
  for (int r = 0; r < 4; r++){
    size_t o = ((size_t)ks * T_STEPS + t0 + ty * 4 + r) * INC + tx * 8;
    *(float4*)&part[o]     = make_float4(acc[r][0], acc[r][1], acc[r][2], acc[r][3]);
    *(float4*)&part[o + 4] = make_float4(acc[r][4], acc[r][5], acc[r][6], acc[r][7]);
  }
}

// ---------------- reduce k-splits -> visit_emb[t][c]
__global__ __launch_bounds__(256) void k_reduce(const float* __restrict__ part,
                                                float* __restrict__ ve){
  int idx = blockIdx.x * 256 + threadIdx.x;   // grid 512 -> 131072 cells
  float s = 0.f;
  #pragma unroll
  for (int ks = 0; ks < KSPLIT; ks++) s += part[(size_t)ks * (T_STEPS * INC) + idx];
  ve[idx] = s;
}

// ---------------- gxq[t][unit][gate] = ve[t]·w_ih[row] + b_ih[row] (+ b_hh for r,z)
__global__ __launch_bounds__(768) void k_gx(const float* __restrict__ ve,
                                            const float* __restrict__ w_ih,
                                            const float* __restrict__ b_ih,
                                            const float* __restrict__ b_hh,
                                            float* __restrict__ gxq){
  const int t = blockIdx.x;
  const int j = threadIdx.x;          // row 0..767
  __shared__ float4 v4[32];
  if (j < 32) v4[j] = *(const float4*)(ve + (size_t)t * INC + j * 4);
  __syncthreads();
  const float4* wr = (const float4*)(w_ih + (size_t)j * INC);
  float a0 = 0.f, a1 = 0.f, a2 = 0.f, a3 = 0.f;
  #pragma unroll
  for (int q = 0; q < 32; q++){
    float4 w = wr[q]; float4 v = v4[q];
    a0 += w.x * v.x; a1 += w.y * v.y; a2 += w.z * v.z; a3 += w.w * v.w;
  }
  float bias = b_ih[j] + (j < 512 ? b_hh[j] : 0.f);
  gxq[(size_t)t * 1024 + (j & 255) * 4 + (j >> 8)] = (a0 + a1) + (a2 + a3) + bias;
}

// ---------------- GRU scan v4: 1024 threads (16 waves, 4/SIMD -> 128-reg budget).
// Lane layout: unit = tid>>2 (0..255), ks = tid&3 (k-quarter of 64).
// Per-lane weights: 196608 halves / 1024 lanes = 96 VGPRs -> fits the 128 cap
// natively (v3's 192-reg demand at 512thr got split 128 arch + ~100 AGPR; each
// AGPR-resident fdot2 operand cost a v_accvgpr_read -> VALU 2157 cyc/step vs
// the 930 model. rocprof: VGPR=128, VALUBusy 0.305).
// 96 fdot2/lane/step; k-reduce = dpp xor1 + xor2 (quad-local, no LDS).
// ds_read rotation: lane reads its 8 chunks starting at chunk 2*ks -> the 4
// distinct addresses per read-slot land in 4 distinct banks (was 4-way).
__global__ __launch_bounds__(1024) void k_gru(const float* __restrict__ w_hh,
                                              const float* __restrict__ b_hh,
                                              const float* __restrict__ gxq,
                                              float* __restrict__ hs){
  const int tid  = threadIdx.x;
  const int unit = tid >> 2;          // 0..255
  const int ks   = tid & 3;           // k-quarter
  const int k0   = ks * 64;

  __shared__ _Float16 hbuf[2][256];

  // register-resident fp16 weights: Bp[gate][32 half2] = 96 VGPRs
  half2v Bp[3][32];
  #pragma unroll
  for (int g = 0; g < 3; g++){
    const float* wr = w_hh + (size_t)(g * 256 + unit) * HIDC + k0;
    #pragma unroll
    for (int c = 0; c < 16; c++){
      float4 v = *(const float4*)(wr + c * 4);
      half2v p0; p0[0] = (_Float16)v.x; p0[1] = (_Float16)v.y;
      half2v p1; p1[0] = (_Float16)v.z; p1[1] = (_Float16)v.w;
      Bp[g][2 * c]     = p0;
      Bp[g][2 * c + 1] = p1;
    }
  }
  const float bn = b_hh[512 + unit];
  float hprev = 0.f;
  if (tid < 256) hbuf[0][tid] = (_Float16)0.f;
  __syncthreads();

  for (int t = 0; t < T_STEPS; t++){
    const _Float16* hb = &hbuf[t & 1][k0];
    // gq load issues now; latency hidden under the 96-deep fdot2 wall
    f32x4 gq = *(const f32x4*)(gxq + (size_t)t * 1024 + unit * 4);

    float ar0 = 0.f, ar1 = 0.f, az0 = 0.f, az1 = 0.f, an0 = 0.f, an1 = 0.f;
    #pragma unroll
    for (int c = 0; c < 8; c++){
      const int cc = (c + 2 * ks) & 7;          // bank-rotated chunk order
      half8 hv = *(const half8*)(hb + cc * 8);  // 16B; 4 addrs/wave, distinct banks
      #pragma unroll
      for (int q = 0; q < 4; q++){
        half2v hp; hp[0] = hv[2 * q]; hp[1] = hv[2 * q + 1];
        const int j = cc * 4 + q;
        if (c & 1){
          ar1 = __builtin_amdgcn_fdot2(hp, Bp[0][j], ar1, false);
          az1 = __builtin_amdgcn_fdot2(hp, Bp[1][j], az1, false);
          an1 = __builtin_amdgcn_fdot2(hp, Bp[2][j], an1, false);
        } else {
          ar0 = __builtin_amdgcn_fdot2(hp, Bp[0][j], ar0, false);
          az0 = __builtin_amdgcn_fdot2(hp, Bp[1][j], az0, false);
          an0 = __builtin_amdgcn_fdot2(hp, Bp[2][j], an0, false);
        }
      }
    }

    float dr = ar0 + ar1; dr += dpp_xor1(dr); dr += dpp_xor2(dr);
    float dz = az0 + az1; dz += dpp_xor1(dz); dz += dpp_xor2(dz);
    float dn = an0 + an1; dn += dpp_xor1(dn); dn += dpp_xor2(dn);

    float r = 1.f / (1.f + __expf(-(gq[0] + dr)));
    float z = 1.f / (1.f + __expf(-(gq[1] + dz)));
    float pre = gq[2] + r * (dn + bn);
    float ax = fabsf(pre);
    float e = __expf(-2.f * ax);
    float th = (1.f - e) / (1.f + e);
    float n = copysignf(th, pre);
    float hnew = n + z * (hprev - n);
    hprev = hnew;
    if (ks == 0){
      hbuf[(t + 1) & 1][unit] = (_Float16)hnew;
      hs[(size_t)t * HIDC + unit] = hnew;
    }
    // publish hbuf write; do NOT drain vmcnt (hs store / gq loads keep flowing)
    asm volatile("s_waitcnt lgkmcnt(0)" ::: "memory");
    __builtin_amdgcn_s_barrier();
    asm volatile("" ::: "memory");
  }
}

// ---------------- logits[t] = hs[t]·w_attn
__global__ __launch_bounds__(64) void k_logits(const float* __restrict__ hs,
                                               const float* __restrict__ w_attn,
                                               float* __restrict__ logits){
  int t = blockIdx.x;
  int l = threadIdx.x;
  float4 hv = *(const float4*)(hs + (size_t)t * HIDC + l * 4);
  float4 wv = *(const float4*)(w_attn + l * 4);
  float p = hv.x * wv.x + hv.y * wv.y + hv.z * wv.z + hv.w * wv.w;
  #pragma unroll
  for (int o = 32; o > 0; o >>= 1) p += __shfl_down(p, o);
  if (l == 0) logits[t] = p;
}

// ---------------- softmax + weighted sum -> out[256]
__global__ __launch_bounds__(1024) void k_attn(const float* __restrict__ logits,
                                               const float* __restrict__ hs,
                                               float* __restrict__ out){
  __shared__ float sm[1024];
  __shared__ float al[1024];
  __shared__ float ps[4][HIDC];
  int tid = threadIdx.x;
  float lg = logits[tid];
  sm[tid] = lg; __syncthreads();
  for (int s = 512; s > 0; s >>= 1){
    if (tid < s) sm[tid] = fmaxf(sm[tid], sm[tid + s]);
    __syncthreads();
  }
  float mx = sm[0]; __syncthreads();
  float e = __expf(lg - mx);
  sm[tid] = e; __syncthreads();
  for (int s = 512; s > 0; s >>= 1){
    if (tid < s) sm[tid] += sm[tid + s];
    __syncthreads();
  }
  float inv = 1.f / sm[0];
  al[tid] = e * inv;
  __syncthreads();
  int c = tid & 255; int tq = tid >> 8;
  float acc = 0.f;
  for (int t = tq; t < T_STEPS; t += 4) acc += al[t] * hs[(size_t)t * HIDC + c];
  ps[tq][c] = acc; __syncthreads();
  if (tid < HIDC) out[tid] = (ps[0][tid] + ps[1][tid]) + (ps[2][tid] + ps[3][tid]);
}

extern "C" void kernel_launch(void* const* d_in, const int* in_sizes, int n_in,
                              void* d_out, int out_size, void* d_ws, size_t ws_size,
                              hipStream_t stream){
  const float* X      = (const float*)d_in[0];
  const float* Hm     = (const float*)d_in[1];
  const float* w_ih   = (const float*)d_in[2];
  const float* w_hh   = (const float*)d_in[3];
  const float* b_ih   = (const float*)d_in[4];
  const float* b_hh   = (const float*)d_in[5];
  const float* w_attn = (const float*)d_in[6];
  float* out = (float*)d_out;

  float* ws     = (float*)d_ws;
  float* part   = ws;                       // 32*1024*128 = 4,194,304 f
  float* ve     = part + 4194304;           // 131,072 f
  float* gxq    = ve + 131072;              // 1024*1024 + 1024 pad = 1,049,600 f
  float* hs     = gxq + 1049600;            // 262,144 f
  float* logits = hs + 262144;              // 1,024 f   (~22.6 MB total)

  k_phase1<<<256, 512, 0, stream>>>(X, Hm, part);
  k_reduce<<<512, 256, 0, stream>>>(part, ve);
  k_gx<<<1024, 768, 0, stream>>>(ve, w_ih, b_ih, b_hh, gxq);
  k_gru<<<1, 1024, 0, stream>>>(w_hh, b_hh, gxq, hs);
  k_logits<<<1024, 64, 0, stream>>>(hs, w_attn, logits);
  k_attn<<<1, 1024, 0, stream>>>(logits, hs, out);
}

// Round 4
// 2211.393 us; speedup vs baseline: 1.2060x; 1.2060x over previous
//
#include <hip/hip_runtime.h>
#include <hip/hip_fp16.h>

typedef _Float16 half8 __attribute__((ext_vector_type(8)));
typedef _Float16 half2v __attribute__((ext_vector_type(2)));
typedef float f32x4 __attribute__((ext_vector_type(4)));

#define T_STEPS 1024
#define INC 128
#define HIDC 256
#define G3 768
#define NN 100000
#define KSPLIT 32
#define NCHUNK 3125   // NN / KSPLIT
#define XS_STRIDE 144 // 16 c-groups * 8 + skew(12) + hf(4): max offset 139 -> stride 144

// quad_perm [1,0,3,2] : xor-1 within each quad, pure-VALU lane exchange
__device__ __forceinline__ float dpp_xor1(float v){
  int t = __builtin_amdgcn_update_dpp(0, __float_as_int(v), 0xB1, 0xF, 0xF, true);
  return __int_as_float(t);
}

// ---------------- Phase 1: partials[ks][t][c] = sum over n-chunk of H[n,t]*X[n,c]
// 256 blocks (1D, XCD-swizzled), 512 threads, tile 128t x 128c, thread-tile 4x8.
__global__ __launch_bounds__(512) void k_phase1(const float* __restrict__ X,
                                                const float* __restrict__ Hm,
                                                float* __restrict__ part){
  const int bid = blockIdx.x;         // 0..255
  const int xcd = bid & 7;
  const int idx = bid >> 3;           // 0..31
  const int ks  = xcd * 4 + (idx & 3);
  const int tt  = idx >> 2;           // 0..7
  const int t0 = tt * 128;
  const int nbeg = ks * NCHUNK;
  const int nend = nbeg + NCHUNK;
  __shared__ float Hs[16][128];
  __shared__ float Xs[16 * XS_STRIDE];   // bank-skewed, stride 144
  const int tid = threadIdx.x;
  const int tx = tid & 15;            // c-group: c0 = tx*8
  const int ty = tid >> 4;            // 0..31 : t rows ty*4..+3
  const int sr = tid >> 5;            // staging row 0..15
  const int sc = tid & 31;            // staging float4 col
  const int xskew = tx * 8 + (tx >> 2) * 4;   // 2-way max bank aliasing

  float acc[4][8];
  #pragma unroll
  for (int r = 0; r < 4; r++)
    #pragma unroll
    for (int q = 0; q < 8; q++) acc[r][q] = 0.f;

  // prologue prefetch (iter 0)
  float4 hv = make_float4(0.f,0.f,0.f,0.f), xv = make_float4(0.f,0.f,0.f,0.f);
  {
    int n = nbeg + sr;
    if (n < nend){
      hv = *(const float4*)(Hm + (size_t)n * T_STEPS + t0 + sc * 4);
      xv = *(const float4*)(X  + (size_t)n * INC + sc * 4);
    }
  }

  for (int n0 = nbeg; n0 < nend; n0 += 16){
    __builtin_amdgcn_s_barrier();     // prev tile's readers done (their own lgkm drained)
    asm volatile("" ::: "memory");
    *(float4*)&Hs[sr][sc * 4] = hv;
    {
      int g = sc >> 1, hf = sc & 1;   // c-group, half
      *(float4*)&Xs[sr * XS_STRIDE + g * 8 + (g >> 2) * 4 + hf * 4] = xv;
    }
    asm volatile("s_waitcnt lgkmcnt(0)" ::: "memory");
    __builtin_amdgcn_s_barrier();     // tile visible to all waves
    asm volatile("" ::: "memory");

    // issue next tile's loads NOW; FMA phase below hides HBM latency
    {
      int nn = n0 + 16 + sr;
      hv = make_float4(0.f,0.f,0.f,0.f);
      xv = make_float4(0.f,0.f,0.f,0.f);
      if (nn < nend){
        hv = *(const float4*)(Hm + (size_t)nn * T_STEPS + t0 + sc * 4);
        xv = *(const float4*)(X  + (size_t)nn * INC + sc * 4);
      }
    }

    #pragma unroll
    for (int i = 0; i < 16; i++){
      float4 h4 = *(const float4*)&Hs[i][ty * 4];
      float4 x0 = *(const float4*)&Xs[i * XS_STRIDE + xskew];
      float4 x1 = *(const float4*)&Xs[i * XS_STRIDE + xskew + 4];
      float xr[8] = {x0.x,x0.y,x0.z,x0.w,x1.x,x1.y,x1.z,x1.w};
      float hr[4] = {h4.x,h4.y,h4.z,h4.w};
      #pragma unroll
      for (int r = 0; r < 4; r++)
        #pragma unroll
        for (int q = 0; q < 8; q++)
          acc[r][q] += hr[r] * xr[q];
    }
  }
  #pragma unroll
  for (int r = 0; r < 4; r++){
    size_t o = ((size_t)ks * T_STEPS + t0 + ty * 4 + r) * INC + tx * 8;
    *(float4*)&part[o]     = make_float4(acc[r][0], acc[r][1], acc[r][2], acc[r][3]);
    *(float4*)&part[o + 4] = make_float4(acc[r][4], acc[r][5], acc[r][6], acc[r][7]);
  }
}

// ---------------- reduce k-splits -> visit_emb[t][c]
__global__ __launch_bounds__(256) void k_reduce(const float* __restrict__ part,
                                                float* __restrict__ ve){
  int idx = blockIdx.x * 256 + threadIdx.x;   // grid 512 -> 131072 cells
  float s = 0.f;
  #pragma unroll
  for (int ks = 0; ks < KSPLIT; ks++) s += part[(size_t)ks * (T_STEPS * INC) + idx];
  ve[idx] = s;
}

// ---------------- gxq[t][unit][gate] = ve[t]·w_ih[row] + b_ih[row] (+ b_hh for r,z)
__global__ __launch_bounds__(768) void k_gx(const float* __restrict__ ve,
                                            const float* __restrict__ w_ih,
                                            const float* __restrict__ b_ih,
                                            const float* __restrict__ b_hh,
                                            float* __restrict__ gxq){
  const int t = blockIdx.x;
  const int j = threadIdx.x;          // row 0..767
  __shared__ float4 v4[32];
  if (j < 32) v4[j] = *(const float4*)(ve + (size_t)t * INC + j * 4);
  __syncthreads();
  const float4* wr = (const float4*)(w_ih + (size_t)j * INC);
  float a0 = 0.f, a1 = 0.f, a2 = 0.f, a3 = 0.f;
  #pragma unroll
  for (int q = 0; q < 32; q++){
    float4 w = wr[q]; float4 v = v4[q];
    a0 += w.x * v.x; a1 += w.y * v.y; a2 += w.z * v.z; a3 += w.w * v.w;
  }
  float bias = b_ih[j] + (j < 512 ? b_hh[j] : 0.f);
  gxq[(size_t)t * 1024 + (j & 255) * 4 + (j >> 8)] = (a0 + a1) + (a2 + a3) + bias;
}

// ---------------- GRU scan v5: round-2 structure (512 thr, 2 lanes/unit,
// 192-reg fp16 weights) + PINNED occupancy.
// Diagnosis across r1-r3: with min-only waves-per-eu, the RA budgets registers
// for 2x the declared occupancy (r2: granted 128 at budget 256; r3: 64 at 128)
// and shunts overflow into AGPRs at a 50:50 split; every AGPR-resident fdot2
// operand then costs a v_accvgpr_read (~1200 extra cyc/step).
// Fix: amdgpu_waves_per_eu(2,2) -> budget is a FIRM 256; demand ~232 fits with
// zero AGPR traffic. Init loads sched_barrier'd every 2 iters so the unrolled
// 64xfloat4 prologue can't spike pressure and bias RA.
// Verification key: VGPR_Count should read ~232-240, not 128.
__global__ __attribute__((amdgpu_flat_work_group_size(512, 512),
                          amdgpu_waves_per_eu(2, 2)))
void k_gru(const float* __restrict__ w_hh,
           const float* __restrict__ b_hh,
           const float* __restrict__ gxq,
           float* __restrict__ hs){
  const int tid  = threadIdx.x;
  const int unit = tid >> 1;          // 0..255
  const int ks   = tid & 1;           // k-half
  const int k0   = ks * 128;

  __shared__ _Float16 hbuf[2][256];

  // register-resident fp16 weights: Bp[gate][64 half2] = 192 VGPRs
  half2v Bp[3][64];
  #pragma unroll
  for (int g = 0; g < 3; g++){
    const float* wr = w_hh + (size_t)(g * 256 + unit) * HIDC + k0;
    #pragma unroll
    for (int c = 0; c < 32; c++){
      float4 v = *(const float4*)(wr + c * 4);
      half2v p0; p0[0] = (_Float16)v.x; p0[1] = (_Float16)v.y;
      half2v p1; p1[0] = (_Float16)v.z; p1[1] = (_Float16)v.w;
      Bp[g][2 * c]     = p0;
      Bp[g][2 * c + 1] = p1;
      if (c & 1) __builtin_amdgcn_sched_barrier(0);  // <=2 loads in flight: no init pressure spike
    }
  }
  const float bn = b_hh[512 + unit];
  float hprev = 0.f;
  if (tid < 256) hbuf[0][tid] = (_Float16)0.f;
  __syncthreads();

  f32x4 gq = *(const f32x4*)(gxq + (size_t)unit * 4);   // t=0

  for (int t = 0; t < T_STEPS; t++){
    const _Float16* hb = &hbuf[t & 1][k0];
    float ar0 = 0.f, ar1 = 0.f, az0 = 0.f, az1 = 0.f, an0 = 0.f, an1 = 0.f;
    #pragma unroll
    for (int c = 0; c < 16; c++){
      half8 hv = *(const half8*)(hb + c * 8);   // 16B, 2 unique addrs/wave: 2-way (free)
      #pragma unroll
      for (int q = 0; q < 4; q++){
        half2v hp; hp[0] = hv[2 * q]; hp[1] = hv[2 * q + 1];
        if (c & 1){
          ar1 = __builtin_amdgcn_fdot2(hp, Bp[0][4 * c + q], ar1, false);
          az1 = __builtin_amdgcn_fdot2(hp, Bp[1][4 * c + q], az1, false);
          an1 = __builtin_amdgcn_fdot2(hp, Bp[2][4 * c + q], an1, false);
        } else {
          ar0 = __builtin_amdgcn_fdot2(hp, Bp[0][4 * c + q], ar0, false);
          az0 = __builtin_amdgcn_fdot2(hp, Bp[1][4 * c + q], az0, false);
          an0 = __builtin_amdgcn_fdot2(hp, Bp[2][4 * c + q], an0, false);
        }
      }
    }
    // prefetch next step's gx (pad row exists at t=1023)
    f32x4 gq_n = *(const f32x4*)(gxq + (size_t)(t + 1) * 1024 + unit * 4);

    float dr = ar0 + ar1; dr += dpp_xor1(dr);   // + other k-half
    float dz = az0 + az1; dz += dpp_xor1(dz);
    float dn = an0 + an1; dn += dpp_xor1(dn);

    float r = 1.f / (1.f + __expf(-(gq[0] + dr)));
    float z = 1.f / (1.f + __expf(-(gq[1] + dz)));
    float pre = gq[2] + r * (dn + bn);
    float ax = fabsf(pre);
    float e = __expf(-2.f * ax);
    float th = (1.f - e) / (1.f + e);
    float n = copysignf(th, pre);
    float hnew = n + z * (hprev - n);
    hprev = hnew;
    if (ks == 0){
      hbuf[(t + 1) & 1][unit] = (_Float16)hnew;
      hs[(size_t)t * HIDC + unit] = hnew;
    }
    gq = gq_n;
    __syncthreads();
  }
}

// ---------------- logits[t] = hs[t]·w_attn
__global__ __launch_bounds__(64) void k_logits(const float* __restrict__ hs,
                                               const float* __restrict__ w_attn,
                                               float* __restrict__ logits){
  int t = blockIdx.x;
  int l = threadIdx.x;
  float4 hv = *(const float4*)(hs + (size_t)t * HIDC + l * 4);
  float4 wv = *(const float4*)(w_attn + l * 4);
  float p = hv.x * wv.x + hv.y * wv.y + hv.z * wv.z + hv.w * wv.w;
  #pragma unroll
  for (int o = 32; o > 0; o >>= 1) p += __shfl_down(p, o);
  if (l == 0) logits[t] = p;
}

// ---------------- softmax + weighted sum -> out[256]
__global__ __launch_bounds__(1024) void k_attn(const float* __restrict__ logits,
                                               const float* __restrict__ hs,
                                               float* __restrict__ out){
  __shared__ float sm[1024];
  __shared__ float al[1024];
  __shared__ float ps[4][HIDC];
  int tid = threadIdx.x;
  float lg = logits[tid];
  sm[tid] = lg; __syncthreads();
  for (int s = 512; s > 0; s >>= 1){
    if (tid < s) sm[tid] = fmaxf(sm[tid], sm[tid + s]);
    __syncthreads();
  }
  float mx = sm[0]; __syncthreads();
  float e = __expf(lg - mx);
  sm[tid] = e; __syncthreads();
  for (int s = 512; s > 0; s >>= 1){
    if (tid < s) sm[tid] += sm[tid + s];
    __syncthreads();
  }
  float inv = 1.f / sm[0];
  al[tid] = e * inv;
  __syncthreads();
  int c = tid & 255; int tq = tid >> 8;
  float acc = 0.f;
  for (int t = tq; t < T_STEPS; t += 4) acc += al[t] * hs[(size_t)t * HIDC + c];
  ps[tq][c] = acc; __syncthreads();
  if (tid < HIDC) out[tid] = (ps[0][tid] + ps[1][tid]) + (ps[2][tid] + ps[3][tid]);
}

extern "C" void kernel_launch(void* const* d_in, const int* in_sizes, int n_in,
                              void* d_out, int out_size, void* d_ws, size_t ws_size,
                              hipStream_t stream){
  const float* X      = (const float*)d_in[0];
  const float* Hm     = (const float*)d_in[1];
  const float* w_ih   = (const float*)d_in[2];
  const float* w_hh   = (const float*)d_in[3];
  const float* b_ih   = (const float*)d_in[4];
  const float* b_hh   = (const float*)d_in[5];
  const float* w_attn = (const float*)d_in[6];
  float* out = (float*)d_out;

  float* ws     = (float*)d_ws;
  float* part   = ws;                       // 32*1024*128 = 4,194,304 f
  float* ve     = part + 4194304;           // 131,072 f
  float* gxq    = ve + 131072;              // 1024*1024 + 1024 pad = 1,049,600 f
  float* hs     = gxq + 1049600;            // 262,144 f
  float* logits = hs + 262144;              // 1,024 f   (~22.6 MB total)

  k_phase1<<<256, 512, 0, stream>>>(X, Hm, part);
  k_reduce<<<512, 256, 0, stream>>>(part, ve);
  k_gx<<<1024, 768, 0, stream>>>(ve, w_ih, b_ih, b_hh, gxq);
  k_gru<<<1, 512, 0, stream>>>(w_hh, b_hh, gxq, hs);
  k_logits<<<1024, 64, 0, stream>>>(hs, w_attn, logits);
  k_attn<<<1, 1024, 0, stream>>>(logits, hs, out);
}